// Round 4
// baseline (38053.796 us; speedup 1.0000x reference)
//
#include <hip/hip_runtime.h>

#define HDIM 512
#define BATCH 32
#define SEQ 128
#define VOCAB 16384
#define NBLK 256      // cooperative grid blocks (1 per CU)
#define NGRU 128      // blocks participating in GRU phase (4 j's each)
#define NTHR 256
#define SLOTP 32      // u32s per barrier slot (128 B line)

typedef unsigned long long u64;
typedef unsigned int u32;

static __device__ __forceinline__ float4 ld4(const float* p) {
    return *reinterpret_cast<const float4*>(p);
}
static __device__ __forceinline__ float dot4(float4 a, float4 b) {
    return a.x*b.x + a.y*b.y + a.z*b.z + a.w*b.w;
}
// monotone float->u32 map: a>b (floats, no NaN) <=> ford(a)>ford(b)
static __device__ __forceinline__ u32 ford(float f) {
    u32 b = __float_as_uint(f);
    return b ^ ((b >> 31) ? 0xFFFFFFFFu : 0x80000000u);
}
static __device__ __forceinline__ u64 shfl_xor_u64(u64 x, int m) {
    int lo = __shfl_xor((int)(u32)x, m);
    int hi = __shfl_xor((int)(u32)(x >> 32), m);
    return ((u64)(u32)hi << 32) | (u32)lo;
}

// ---- contention-free device barrier ----
// Arrival: each block release-stores its monotonic count to its OWN 128B slot.
// Gather: master (block 0) thread i polls slot i (read-only, parallel).
// Broadcast: master release-stores epoch to 8 replicated lines; block b polls
// line (b&7) read-only. No cacheline is RMW'd or multi-written => no ping-pong.
// Monotonic targets => race-free across barrier instances without resets
// (within one launch; slots/epochs zeroed by init_kernel each call).
static __device__ __forceinline__ void xbar(int blk, int tid, u32* slots,
                                            u32* eps, u32 target, int nblk) {
    __syncthreads();
    if (blk == 0) {
        if (tid > 0 && tid < nblk) {
            const u32* s = slots + tid * SLOTP;
            int i = 0;
            while (__hip_atomic_load(s, __ATOMIC_ACQUIRE, __HIP_MEMORY_SCOPE_AGENT) < target) {
                if (++i > 2) __builtin_amdgcn_s_sleep(1);
            }
        }
        __syncthreads();
        if (tid < 8)
            __hip_atomic_store(eps + tid * SLOTP, target, __ATOMIC_RELEASE,
                               __HIP_MEMORY_SCOPE_AGENT);
    } else {
        if (tid == 0) {
            __hip_atomic_store(slots + blk * SLOTP, target, __ATOMIC_RELEASE,
                               __HIP_MEMORY_SCOPE_AGENT);
            const u32* e = eps + (blk & 7) * SLOTP;
            int i = 0;
            while (__hip_atomic_load(e, __ATOMIC_ACQUIRE, __HIP_MEMORY_SCOPE_AGENT) < target) {
                if (++i > 2) __builtin_amdgcn_s_sleep(1);
            }
        }
        __syncthreads();
    }
}

// GRU body — bit-identical arithmetic to the round-1/2/3 passing kernels.
static __device__ __forceinline__ void gru_body(
    int blk, int tid, const int* toks,
    const float* __restrict__ hin, float* __restrict__ hout,
    const float* __restrict__ Wih, const float* __restrict__ Whh,
    const float* __restrict__ bih, const float* __restrict__ bhh,
    const float* __restrict__ emb)
{
    const int wave = tid >> 6;
    const int lane = tid & 63;
    const int kh   = lane >> 5;
    const int b    = lane & 31;
    const int j    = blk * 4 + wave;

    const int tok = toks[b];
    const float* xrow = emb + (size_t)tok * HDIM + kh * 256;
    const float* hrow = hin + b * HDIM + kh * 256;
    const float* wir = Wih + (size_t)(0*HDIM + j) * HDIM + kh * 256;
    const float* wiz = Wih + (size_t)(1*HDIM + j) * HDIM + kh * 256;
    const float* win = Wih + (size_t)(2*HDIM + j) * HDIM + kh * 256;
    const float* whr = Whh + (size_t)(0*HDIM + j) * HDIM + kh * 256;
    const float* whz = Whh + (size_t)(1*HDIM + j) * HDIM + kh * 256;
    const float* whn = Whh + (size_t)(2*HDIM + j) * HDIM + kh * 256;

    float pr = 0.f, pz = 0.f, pxn = 0.f, phn = 0.f;
    #pragma unroll 4
    for (int k4 = 0; k4 < 64; ++k4) {
        float4 x4 = ld4(xrow + k4*4);
        float4 h4 = ld4(hrow + k4*4);
        pr  += dot4(x4, ld4(wir + k4*4)) + dot4(h4, ld4(whr + k4*4));
        pz  += dot4(x4, ld4(wiz + k4*4)) + dot4(h4, ld4(whz + k4*4));
        pxn += dot4(x4, ld4(win + k4*4));
        phn += dot4(h4, ld4(whn + k4*4));
    }
    pr  += __shfl_xor(pr, 32);
    pz  += __shfl_xor(pz, 32);
    pxn += __shfl_xor(pxn, 32);
    phn += __shfl_xor(phn, 32);

    if (kh == 0) {
        float r = 1.f / (1.f + expf(-(pr + bih[j]      + bhh[j])));
        float z = 1.f / (1.f + expf(-(pz + bih[HDIM+j] + bhh[HDIM+j])));
        float n = tanhf(pxn + bih[2*HDIM+j] + r * (phn + bhh[2*HDIM+j]));
        float hprev = hin[b * HDIM + j];
        hout[b * HDIM + j] = (1.f - z) * n + z * hprev;
    }
}

// log_softmax over one 16384-row, 256 threads
static __device__ __forceinline__ void softmax_row(float* p, int tid,
                                                   float* redm, float* reds) {
    float4 vals[16];
    float m = -3.4e38f;
    #pragma unroll
    for (int i = 0; i < 16; ++i) {
        vals[i] = ld4(p + (i * 256 + tid) * 4);
        m = fmaxf(m, fmaxf(fmaxf(vals[i].x, vals[i].y), fmaxf(vals[i].z, vals[i].w)));
    }
    #pragma unroll
    for (int d = 1; d < 64; d <<= 1) m = fmaxf(m, __shfl_xor(m, d));
    if ((tid & 63) == 0) redm[tid >> 6] = m;
    __syncthreads();
    m = fmaxf(fmaxf(redm[0], redm[1]), fmaxf(redm[2], redm[3]));

    float s = 0.f;
    #pragma unroll
    for (int i = 0; i < 16; ++i) {
        s += expf(vals[i].x - m) + expf(vals[i].y - m)
           + expf(vals[i].z - m) + expf(vals[i].w - m);
    }
    #pragma unroll
    for (int d = 1; d < 64; d <<= 1) s += __shfl_xor(s, d);
    if ((tid & 63) == 0) reds[tid >> 6] = s;
    __syncthreads();
    s = reds[0] + reds[1] + reds[2] + reds[3];

    const float lg = m + logf(s);
    #pragma unroll
    for (int i = 0; i < 16; ++i) {
        float4 r;
        r.x = vals[i].x - lg; r.y = vals[i].y - lg;
        r.z = vals[i].z - lg; r.w = vals[i].w - lg;
        *reinterpret_cast<float4*>(p + (i * 256 + tid) * 4) = r;
    }
    __syncthreads();   // redm/reds reused next row
}

// ==================== persistent cooperative kernel ====================
__global__ __launch_bounds__(NTHR, 1) void seq2seq_main(
    const int* __restrict__ input,
    const float* __restrict__ enc_emb, const float* __restrict__ enc_Wih,
    const float* __restrict__ enc_Whh, const float* __restrict__ enc_bih,
    const float* __restrict__ enc_bhh,
    const float* __restrict__ dec_emb, const float* __restrict__ dec_Wih,
    const float* __restrict__ dec_Whh, const float* __restrict__ dec_bih,
    const float* __restrict__ dec_bhh,
    const float* __restrict__ out_W, const float* __restrict__ out_b,
    float* __restrict__ out, float* h0, float* h1, u64* pk, u32* bar)
{
    __shared__ int tok_s[BATCH];
    __shared__ u64 redk[BATCH][8];
    __shared__ float part[4][64][33];
    __shared__ float redm[4];
    __shared__ float reds[4];

    const int tid = threadIdx.x;
    const int blk = blockIdx.x;

    u32* slots_enc = bar;                              // 128 slots
    u32* slots_all = bar + 128 * SLOTP;                // 256 slots
    u32* ep_enc    = bar + (128 + 256) * SLOTP;        // 8 lines
    u32* ep_all    = ep_enc + 8 * SLOTP;               // 8 lines

    // ---- encoder: 128 steps, only blocks < NGRU participate ----
    if (blk < NGRU) {
        for (int t = 0; t < SEQ; ++t) {
            float* hin  = (t & 1) ? h1 : h0;
            float* hout = (t & 1) ? h0 : h1;
            if (tid < BATCH) tok_s[tid] = input[tid * SEQ + t];
            __syncthreads();
            gru_body(blk, tid, tok_s, hin, hout,
                     enc_Wih, enc_Whh, enc_bih, enc_bhh, enc_emb);
            xbar(blk, tid, slots_enc, ep_enc, (u32)(t + 1), NGRU);
        }
    }

    // ---- decoder: 128 steps ----
    for (int t = 0; t < SEQ; ++t) {
        float* hin  = (t & 1) ? h1 : h0;
        float* hout = (t & 1) ? h0 : h1;

        if (blk < NGRU) {
            if (t == 0) {
                if (tid < BATCH) tok_s[tid] = 0;   // SOS
            } else {
                const int b8 = tid >> 3, c8 = tid & 7;
                const u64* p = pk + b8 * NBLK + c8 * 32;
                u64 best = p[0];
                #pragma unroll 4
                for (int k = 1; k < 32; ++k) { u64 v = p[k]; if (v > best) best = v; }
                redk[b8][c8] = best;
                __syncthreads();
                if (tid < BATCH) {
                    u64 bb = redk[tid][0];
                    #pragma unroll
                    for (int c2 = 1; c2 < 8; ++c2) { u64 v = redk[tid][c2]; if (v > bb) bb = v; }
                    tok_s[tid] = (int)(~(u32)bb);
                }
            }
            __syncthreads();
            gru_body(blk, tid, tok_s, hin, hout,
                     dec_Wih, dec_Whh, dec_bih, dec_bhh, dec_emb);
        }
        xbar(blk, tid, slots_all, ep_all, (u32)(2 * t + 1), NBLK);  // h ready

        // ---- logits + argmax partials: all 256 blocks, 64 vocab rows each ----
        {
            const int vloc = tid & 63;
            const int ks   = __builtin_amdgcn_readfirstlane(tid >> 6);
            const int v    = blk * 64 + vloc;

            float acc[BATCH];
            #pragma unroll
            for (int b = 0; b < BATCH; ++b) acc[b] = 0.f;

            const float* wrow = out_W + (size_t)v * HDIM + ks * 128;
            const float* hq   = hout + ks * 128;

            for (int k4 = 0; k4 < 32; ++k4) {
                float4 w4 = ld4(wrow + k4*4);
                #pragma unroll
                for (int b = 0; b < BATCH; ++b) {
                    acc[b] += dot4(w4, ld4(hq + b * HDIM + k4*4));
                }
            }
            #pragma unroll
            for (int b = 0; b < BATCH; ++b) part[ks][vloc][b] = acc[b];
            __syncthreads();

            const int bg = tid >> 6;
            const float vbias = out_b[v];
            #pragma unroll
            for (int i = 0; i < 8; ++i) {
                const int b = bg * 8 + i;
                float s = part[0][vloc][b] + part[1][vloc][b]
                        + part[2][vloc][b] + part[3][vloc][b] + vbias;
                out[(size_t)b * (SEQ * VOCAB) + (size_t)t * VOCAB + v] = s;

                u64 key = ((u64)ford(s) << 32) | (u32)(~(u32)v);
                #pragma unroll
                for (int d = 1; d < 64; d <<= 1) {
                    u64 o = shfl_xor_u64(key, d);
                    if (o > key) key = o;
                }
                if (vloc == 0) pk[b * NBLK + blk] = key;
            }
        }
        xbar(blk, tid, slots_all, ep_all, (u32)(2 * t + 2), NBLK);  // pk ready
    }

    // ---- folded log_softmax: 16 rows per block ----
    for (int i = 0; i < 16; ++i)
        softmax_row(out + (size_t)(blk * 16 + i) * VOCAB, tid, redm, reds);

    // ---- final decoder hidden -> out tail (h in h0 after t=127) ----
    if (blk < 16) {
        *reinterpret_cast<float4*>(out + (size_t)BATCH * SEQ * VOCAB + blk * 1024 + tid * 4) =
            ld4(h0 + blk * 1024 + tid * 4);
    }
}

// ---- init: zero h0 + barrier area (every call; ws not re-poisoned) ----
#define BAR_U32 ((128 + 256 + 16) * SLOTP)
__global__ __launch_bounds__(256) void init_kernel(float* __restrict__ h0,
                                                   u32* __restrict__ bar) {
    int i = blockIdx.x * 256 + threadIdx.x;
    if (i < BATCH * HDIM) h0[i] = 0.f;
    if (i < BAR_U32) bar[i] = 0;
}

// ==================== fallback multi-kernel path ====================
__global__ __launch_bounds__(256) void gru_step(
    const float* __restrict__ h_in, float* __restrict__ h_out,
    const float* __restrict__ Wih, const float* __restrict__ Whh,
    const float* __restrict__ bih, const float* __restrict__ bhh,
    const float* __restrict__ emb,
    const int* __restrict__ enc_tokens, int t, const u64* __restrict__ pk)
{
    __shared__ int tok_s[BATCH];
    __shared__ u64 redk[BATCH][8];
    const int tid = threadIdx.x;

    if (enc_tokens != nullptr) {
        if (tid < BATCH) tok_s[tid] = enc_tokens[tid * SEQ + t];
    } else if (t == 0) {
        if (tid < BATCH) tok_s[tid] = 0;
    } else {
        const int b8 = tid >> 3, c8 = tid & 7;
        const u64* p = pk + b8 * NBLK + c8 * 32;
        u64 best = p[0];
        #pragma unroll 4
        for (int k = 1; k < 32; ++k) { u64 v = p[k]; if (v > best) best = v; }
        redk[b8][c8] = best;
        __syncthreads();
        if (tid < BATCH) {
            u64 bb = redk[tid][0];
            #pragma unroll
            for (int c2 = 1; c2 < 8; ++c2) { u64 v = redk[tid][c2]; if (v > bb) bb = v; }
            tok_s[tid] = (int)(~(u32)bb);
        }
    }
    __syncthreads();
    gru_body(blockIdx.x, tid, tok_s, h_in, h_out, Wih, Whh, bih, bhh, emb);
}

__global__ __launch_bounds__(256) void logits_kernel(
    const float* __restrict__ h, const float* __restrict__ outW,
    const float* __restrict__ outb, float* __restrict__ out,
    int t, u64* __restrict__ pk)
{
    __shared__ float part[4][64][33];
    const int tid  = threadIdx.x;
    const int vloc = tid & 63;
    const int ks   = __builtin_amdgcn_readfirstlane(tid >> 6);
    const int v    = blockIdx.x * 64 + vloc;

    float acc[BATCH];
    #pragma unroll
    for (int b = 0; b < BATCH; ++b) acc[b] = 0.f;

    const float* wrow = outW + (size_t)v * HDIM + ks * 128;
    const float* hq   = h + ks * 128;

    for (int k4 = 0; k4 < 32; ++k4) {
        float4 w4 = ld4(wrow + k4*4);
        #pragma unroll
        for (int b = 0; b < BATCH; ++b) acc[b] += dot4(w4, ld4(hq + b * HDIM + k4*4));
    }
    #pragma unroll
    for (int b = 0; b < BATCH; ++b) part[ks][vloc][b] = acc[b];
    __syncthreads();

    const int bg = tid >> 6;
    const float vbias = outb[v];
    #pragma unroll
    for (int i = 0; i < 8; ++i) {
        const int b = bg * 8 + i;
        float s = part[0][vloc][b] + part[1][vloc][b]
                + part[2][vloc][b] + part[3][vloc][b] + vbias;
        out[(size_t)b * (SEQ * VOCAB) + (size_t)t * VOCAB + v] = s;
        u64 key = ((u64)ford(s) << 32) | (u32)(~(u32)v);
        #pragma unroll
        for (int d = 1; d < 64; d <<= 1) {
            u64 o = shfl_xor_u64(key, d);
            if (o > key) key = o;
        }
        if (vloc == 0) pk[b * NBLK + blockIdx.x] = key;
    }
}

__global__ __launch_bounds__(256) void copy_kernel(const float* __restrict__ src,
                                                   float* __restrict__ dst, int n) {
    int i = blockIdx.x * 256 + threadIdx.x;
    if (i < n) dst[i] = src[i];
}

__global__ __launch_bounds__(256) void softmax_kernel(float* __restrict__ out) {
    __shared__ float redm[4];
    __shared__ float reds[4];
    softmax_row(out + (size_t)blockIdx.x * VOCAB, threadIdx.x, redm, reds);
}

extern "C" void kernel_launch(void* const* d_in, const int* in_sizes, int n_in,
                              void* d_out, int out_size, void* d_ws, size_t ws_size,
                              hipStream_t stream) {
    const int*   input    = (const int*)  d_in[0];
    const float* enc_emb  = (const float*)d_in[1];
    const float* enc_Wih  = (const float*)d_in[2];
    const float* enc_Whh  = (const float*)d_in[3];
    const float* enc_bih  = (const float*)d_in[4];
    const float* enc_bhh  = (const float*)d_in[5];
    const float* dec_emb  = (const float*)d_in[6];
    const float* dec_Wih  = (const float*)d_in[7];
    const float* dec_Whh  = (const float*)d_in[8];
    const float* dec_bih  = (const float*)d_in[9];
    const float* dec_bhh  = (const float*)d_in[10];
    const float* out_W    = (const float*)d_in[11];
    const float* out_b    = (const float*)d_in[12];

    float* out = (float*)d_out;
    float* ws  = (float*)d_ws;

    float* h0 = ws;                                   // 16384 f
    float* h1 = ws + BATCH * HDIM;                    // 16384 f
    u64*   pk = (u64*)(ws + 2 * BATCH * HDIM);        // 8192 u64 (=16384 f)
    u32*   bar = (u32*)(ws + 4 * BATCH * HDIM);       // 12800 u32

    init_kernel<<<dim3(64), dim3(256), 0, stream>>>(h0, bar);

    void* args[] = {
        (void*)&input, (void*)&enc_emb, (void*)&enc_Wih, (void*)&enc_Whh,
        (void*)&enc_bih, (void*)&enc_bhh,
        (void*)&dec_emb, (void*)&dec_Wih, (void*)&dec_Whh, (void*)&dec_bih,
        (void*)&dec_bhh, (void*)&out_W, (void*)&out_b,
        (void*)&out, (void*)&h0, (void*)&h1, (void*)&pk, (void*)&bar
    };
    hipError_t rc = hipLaunchCooperativeKernel((void*)seq2seq_main,
                                               dim3(NBLK), dim3(NTHR),
                                               args, 0, stream);
    if (rc != hipSuccess) {
        // fallback: multi-kernel path
        float* hb[2] = { h0, h1 };
        for (int t = 0; t < SEQ; ++t) {
            gru_step<<<dim3(NGRU), dim3(256), 0, stream>>>(
                hb[t & 1], hb[(t + 1) & 1],
                enc_Wih, enc_Whh, enc_bih, enc_bhh, enc_emb, input, t, nullptr);
        }
        for (int t = 0; t < SEQ; ++t) {
            gru_step<<<dim3(NGRU), dim3(256), 0, stream>>>(
                hb[t & 1], hb[(t + 1) & 1],
                dec_Wih, dec_Whh, dec_bih, dec_bhh, dec_emb, nullptr, t, pk);
            logits_kernel<<<dim3(NBLK), dim3(256), 0, stream>>>(
                hb[(t + 1) & 1], out_W, out_b, out, t, pk);
        }
        copy_kernel<<<dim3((BATCH * HDIM + 255) / 256), dim3(256), 0, stream>>>(
            h0, out + (size_t)BATCH * SEQ * VOCAB, BATCH * HDIM);
        softmax_kernel<<<dim3(BATCH * SEQ), dim3(256), 0, stream>>>(out);
    }
}

// Round 5
// 15395.415 us; speedup vs baseline: 2.4718x; 2.4718x over previous
//
#include <hip/hip_runtime.h>

#define HDIM 512
#define BATCH 32
#define SEQ 128
#define VOCAB 16384
#define NBLK 256      // grid blocks (1 per CU)
#define NGRU 128      // blocks running the GRU phase (4 j's each)
#define NTHR 256
#define SLOTP 32      // u32s per barrier line (128 B)
#define HLDS_W 516    // padded LDS row width in floats (4-way instead of 32-way)

typedef unsigned long long u64;
typedef unsigned int u32;

// ---------- relaxed agent-scope (MALL-coherent, no L2 inv/wb) accessors ----------
static __device__ __forceinline__ u64 aload64(const u64* p) {
    return __hip_atomic_load(p, __ATOMIC_RELAXED, __HIP_MEMORY_SCOPE_AGENT);
}
static __device__ __forceinline__ void astore64(u64* p, u64 v) {
    __hip_atomic_store(p, v, __ATOMIC_RELAXED, __HIP_MEMORY_SCOPE_AGENT);
}
static __device__ __forceinline__ u32 aload32(const u32* p) {
    return __hip_atomic_load(p, __ATOMIC_RELAXED, __HIP_MEMORY_SCOPE_AGENT);
}
static __device__ __forceinline__ void astore32f(float* p, float v) {
    __hip_atomic_store((u32*)p, __float_as_uint(v), __ATOMIC_RELAXED,
                       __HIP_MEMORY_SCOPE_AGENT);
}

static __device__ __forceinline__ float4 ld4(const float* p) {
    return *reinterpret_cast<const float4*>(p);
}
static __device__ __forceinline__ float dot4(float4 a, float4 b) {
    return a.x*b.x + a.y*b.y + a.z*b.z + a.w*b.w;
}
static __device__ __forceinline__ u32 ford(float f) {   // monotone float->u32
    u32 b = __float_as_uint(f);
    return b ^ ((b >> 31) ? 0xFFFFFFFFu : 0x80000000u);
}
static __device__ __forceinline__ u64 shfl_xor_u64(u64 x, int m) {
    int lo = __shfl_xor((int)(u32)x, m);
    int hi = __shfl_xor((int)(u32)(x >> 32), m);
    return ((u64)(u32)hi << 32) | (u32)lo;
}

// ---------- device barrier: relaxed atomics only, 8 padded group counters ----------
// Producer ordering: __syncthreads() (compiler drains vmcnt per wave) + explicit
// vmcnt(0), then a relaxed fetch_add at MALL. Consumer: relaxed polls; loads
// issued after poll-exit are in-order => see producer data at MALL. No acquire/
// release => no buffer_inv / buffer_wbl2 => L2 stays warm.
static __device__ __forceinline__ void dbar(u32* cnts, u32 target, int blk, int tid) {
    __syncthreads();
    asm volatile("s_waitcnt vmcnt(0)" ::: "memory");
    if (tid == 0)
        __hip_atomic_fetch_add(&cnts[(blk & 7) * SLOTP], 1u,
                               __ATOMIC_RELAXED, __HIP_MEMORY_SCOPE_AGENT);
    if (tid < 64) {   // wave 0 polls all 8 group lines in parallel
        int it = 0;
        for (;;) {
            u32 v = target;
            if (tid < 8) v = aload32(&cnts[tid * SLOTP]);
            if (__ballot(v >= target) == ~0ull) break;
            if (++it > 48) __builtin_amdgcn_s_sleep(8);
            else if (it > 3) __builtin_amdgcn_s_sleep(1);
        }
    }
    __syncthreads();
    asm volatile("" ::: "memory");
}

// ---------- stage full h (32x512 f32, 64KB) into LDS via coalesced sc1 loads ----------
static __device__ __forceinline__ void stage_h(float* hlf, const float* hglob, int tid) {
    const u64* src = (const u64*)hglob;
    #pragma unroll
    for (int it = 0; it < 32; ++it) {
        int q = it * NTHR + tid;          // u64 index 0..8191
        int w = q * 2;                    // float index
        int b = w >> 9, k = w & 511;
        u64 v = aload64(src + q);
        *reinterpret_cast<u64*>(hlf + b * HLDS_W + k) = v;
    }
}

// ---------- GRU core: bit-identical arithmetic; h from LDS; h_out via sc1 ----------
static __device__ __forceinline__ void gru_core(
    int blk, int tid, const int* toks, const float* hlf, float* hout,
    const float* __restrict__ Wih, const float* __restrict__ Whh,
    const float* __restrict__ bih, const float* __restrict__ bhh,
    const float* __restrict__ emb)
{
    const int wave = tid >> 6;
    const int lane = tid & 63;
    const int kh   = lane >> 5;
    const int b    = lane & 31;
    const int j    = blk * 4 + wave;

    const int tok = toks[b];
    const float* xrow = emb + (size_t)tok * HDIM + kh * 256;
    const float* hrow = hlf + b * HLDS_W + kh * 256;
    const float* wir = Wih + (size_t)(0*HDIM + j) * HDIM + kh * 256;
    const float* wiz = Wih + (size_t)(1*HDIM + j) * HDIM + kh * 256;
    const float* win = Wih + (size_t)(2*HDIM + j) * HDIM + kh * 256;
    const float* whr = Whh + (size_t)(0*HDIM + j) * HDIM + kh * 256;
    const float* whz = Whh + (size_t)(1*HDIM + j) * HDIM + kh * 256;
    const float* whn = Whh + (size_t)(2*HDIM + j) * HDIM + kh * 256;

    float pr = 0.f, pz = 0.f, pxn = 0.f, phn = 0.f;
    #pragma unroll 4
    for (int k4 = 0; k4 < 64; ++k4) {
        float4 x4 = ld4(xrow + k4*4);
        float4 h4 = ld4(hrow + k4*4);
        pr  += dot4(x4, ld4(wir + k4*4)) + dot4(h4, ld4(whr + k4*4));
        pz  += dot4(x4, ld4(wiz + k4*4)) + dot4(h4, ld4(whz + k4*4));
        pxn += dot4(x4, ld4(win + k4*4));
        phn += dot4(h4, ld4(whn + k4*4));
    }
    pr  += __shfl_xor(pr, 32);
    pz  += __shfl_xor(pz, 32);
    pxn += __shfl_xor(pxn, 32);
    phn += __shfl_xor(phn, 32);

    if (kh == 0) {
        float r = 1.f / (1.f + expf(-(pr + bih[j]      + bhh[j])));
        float z = 1.f / (1.f + expf(-(pz + bih[HDIM+j] + bhh[HDIM+j])));
        float n = tanhf(pxn + bih[2*HDIM+j] + r * (phn + bhh[2*HDIM+j]));
        float hprev = hlf[b * HLDS_W + j];
        astore32f(hout + b * HDIM + j, (1.f - z) * n + z * hprev);
    }
}

// ---------- logits core: per-thread 4 k-quarter accumulators (exact order
// match with the old part[4]-combine), h from LDS (uniform reads) ----------
static __device__ __forceinline__ void logits_core(
    int blk, int tid, const float* hlf,
    const float* __restrict__ outW, const float* __restrict__ outb,
    float* __restrict__ out, int t, u64* pk)
{
    const int vloc = tid & 63;
    const int bq   = tid >> 6;
    const int v    = blk * 64 + vloc;
    const float* wrow = outW + (size_t)v * HDIM;

    float acc[4][8];
    #pragma unroll
    for (int q = 0; q < 4; ++q)
        #pragma unroll
        for (int i = 0; i < 8; ++i) acc[q][i] = 0.f;

    #pragma unroll
    for (int q = 0; q < 4; ++q) {
        for (int k4 = 0; k4 < 32; ++k4) {
            float4 w4 = ld4(wrow + q*128 + k4*4);
            #pragma unroll
            for (int i = 0; i < 8; ++i) {
                float4 h4 = ld4(hlf + (bq*8 + i) * HLDS_W + q*128 + k4*4);
                acc[q][i] += dot4(w4, h4);
            }
        }
    }

    const float vbias = outb[v];
    #pragma unroll
    for (int i = 0; i < 8; ++i) {
        const int b = bq*8 + i;
        float s = ((acc[0][i] + acc[1][i]) + acc[2][i]) + acc[3][i] + vbias;
        out[(size_t)b * (SEQ * VOCAB) + (size_t)t * VOCAB + v] = s;

        u64 key = ((u64)ford(s) << 32) | (u32)(~(u32)v);
        #pragma unroll
        for (int d = 1; d < 64; d <<= 1) {
            u64 o = shfl_xor_u64(key, d);
            if (o > key) key = o;
        }
        if (vloc == 0) astore64(pk + b * NBLK + blk, key);
    }
}

// ---------- argmax finalize (tokens from pk partials), coalesced sc1 reads ----------
static __device__ __forceinline__ void argmax_finalize(
    int tid, const u64* pk, u64 (*redk)[8], int* tok_s)
{
    const int fb = tid >> 3, kc = tid & 7;
    const u64* p = pk + fb * NBLK;
    u64 best = aload64(p + kc);
    #pragma unroll 4
    for (int k = 1; k < 32; ++k) {
        u64 x = aload64(p + kc + k * 8);
        if (x > best) best = x;
    }
    redk[fb][kc] = best;
    __syncthreads();
    if (tid < BATCH) {
        u64 bb = redk[tid][0];
        #pragma unroll
        for (int c = 1; c < 8; ++c) { u64 x = redk[tid][c]; if (x > bb) bb = x; }
        tok_s[tid] = (int)(~(u32)bb);
    }
}

// ---------- log_softmax over one 16384-row ----------
static __device__ __forceinline__ void softmax_row(float* p, int tid,
                                                   float* redm, float* reds) {
    float4 vals[16];
    float m = -3.4e38f;
    #pragma unroll
    for (int i = 0; i < 16; ++i) {
        vals[i] = ld4(p + (i * 256 + tid) * 4);
        m = fmaxf(m, fmaxf(fmaxf(vals[i].x, vals[i].y), fmaxf(vals[i].z, vals[i].w)));
    }
    #pragma unroll
    for (int d = 1; d < 64; d <<= 1) m = fmaxf(m, __shfl_xor(m, d));
    if ((tid & 63) == 0) redm[tid >> 6] = m;
    __syncthreads();
    m = fmaxf(fmaxf(redm[0], redm[1]), fmaxf(redm[2], redm[3]));

    float s = 0.f;
    #pragma unroll
    for (int i = 0; i < 16; ++i) {
        s += expf(vals[i].x - m) + expf(vals[i].y - m)
           + expf(vals[i].z - m) + expf(vals[i].w - m);
    }
    #pragma unroll
    for (int d = 1; d < 64; d <<= 1) s += __shfl_xor(s, d);
    if ((tid & 63) == 0) reds[tid >> 6] = s;
    __syncthreads();
    s = reds[0] + reds[1] + reds[2] + reds[3];

    const float lg = m + logf(s);
    #pragma unroll
    for (int i = 0; i < 16; ++i) {
        float4 r;
        r.x = vals[i].x - lg; r.y = vals[i].y - lg;
        r.z = vals[i].z - lg; r.w = vals[i].w - lg;
        *reinterpret_cast<float4*>(p + (i * 256 + tid) * 4) = r;
    }
    __syncthreads();
}

// ==================== persistent cooperative kernel ====================
__global__ __launch_bounds__(NTHR, 1) void seq2seq_main(
    const int* __restrict__ input,
    const float* __restrict__ enc_emb, const float* __restrict__ enc_Wih,
    const float* __restrict__ enc_Whh, const float* __restrict__ enc_bih,
    const float* __restrict__ enc_bhh,
    const float* __restrict__ dec_emb, const float* __restrict__ dec_Wih,
    const float* __restrict__ dec_Whh, const float* __restrict__ dec_bih,
    const float* __restrict__ dec_bhh,
    const float* __restrict__ out_W, const float* __restrict__ out_b,
    float* __restrict__ out, float* h0, float* h1, u64* pk, u32* bar)
{
    __shared__ __align__(16) float hl[BATCH][HLDS_W];   // 66048 B
    __shared__ int tok_s[BATCH];
    __shared__ u64 redk[BATCH][8];
    __shared__ float redm[4];
    __shared__ float reds[4];

    const int tid = threadIdx.x;
    const int blk = blockIdx.x;
    float* hlf = &hl[0][0];

    u32* cEnc = bar;                 // 8 lines, 128 blocks, 16/group
    u32* cA   = bar +  8 * SLOTP;    // 8 lines, 256 blocks, 32/group
    u32* cB   = bar + 16 * SLOTP;
    u32* cF   = bar + 24 * SLOTP;

    // ---- encoder: 128 steps, blocks < NGRU ----
    if (blk < NGRU) {
        for (int t = 0; t < SEQ; ++t) {
            float* hin  = (t & 1) ? h1 : h0;
            float* hout = (t & 1) ? h0 : h1;
            if (tid < BATCH) tok_s[tid] = input[tid * SEQ + t];
            stage_h(hlf, hin, tid);
            __syncthreads();
            gru_core(blk, tid, tok_s, hlf, hout,
                     enc_Wih, enc_Whh, enc_bih, enc_bhh, enc_emb);
            dbar(cEnc, (u32)(t + 1) * 16, blk, tid);
        }
    }

    // ---- decoder: 128 steps ----
    for (int t = 0; t < SEQ; ++t) {
        float* hin  = (t & 1) ? h1 : h0;
        float* hout = (t & 1) ? h0 : h1;

        if (blk < NGRU) {
            if (t == 0) {
                if (tid < BATCH) tok_s[tid] = 0;   // SOS
                __syncthreads();
            } else {
                argmax_finalize(tid, pk, redk, tok_s);   // has internal sync
            }
            stage_h(hlf, hin, tid);
            __syncthreads();
            gru_core(blk, tid, tok_s, hlf, hout,
                     dec_Wih, dec_Whh, dec_bih, dec_bhh, dec_emb);
        }
        dbar(cA, (u32)(t + 1) * 32, blk, tid);       // h_out ready

        stage_h(hlf, hout, tid);
        __syncthreads();
        logits_core(blk, tid, hlf, out_W, out_b, out, t, pk);
        dbar(cB, (u32)(t + 1) * 32, blk, tid);       // pk ready
    }

    // ---- flush dirty logits (one-time) and invalidate stale copies ----
    __threadfence();
    dbar(cF, 32, blk, tid);

    // ---- folded log_softmax: 16 rows per block ----
    for (int i = 0; i < 16; ++i)
        softmax_row(out + (size_t)(blk * 16 + i) * VOCAB, tid, redm, reds);

    // ---- final decoder hidden (h0 after t=127) -> out tail ----
    if (blk < 16) {
        const u64* s = (const u64*)h0;
        u64* d = (u64*)(out + (size_t)BATCH * SEQ * VOCAB);
        #pragma unroll
        for (int k = 0; k < 2; ++k) {
            int idx = blk * 512 + k * 256 + tid;
            d[idx] = aload64(s + idx);
        }
    }
}

// ---- init: zero h0 + barrier area (ws is not re-poisoned between replays) ----
#define BAR_U32 (32 * SLOTP)
__global__ __launch_bounds__(256) void init_kernel(float* __restrict__ h0,
                                                   u32* __restrict__ bar) {
    int i = blockIdx.x * 256 + threadIdx.x;
    if (i < BATCH * HDIM) h0[i] = 0.f;
    if (i < BAR_U32) bar[i] = 0;
}

// ==================== fallback multi-kernel path ====================
__global__ __launch_bounds__(256) void gru_step_fb(
    const float* __restrict__ h_in, float* __restrict__ h_out,
    const float* __restrict__ Wih, const float* __restrict__ Whh,
    const float* __restrict__ bih, const float* __restrict__ bhh,
    const float* __restrict__ emb,
    const int* __restrict__ enc_tokens, int t, const u64* __restrict__ pk)
{
    __shared__ __align__(16) float hl[BATCH][HLDS_W];
    __shared__ int tok_s[BATCH];
    __shared__ u64 redk[BATCH][8];
    const int tid = threadIdx.x;

    if (enc_tokens != nullptr) {
        if (tid < BATCH) tok_s[tid] = enc_tokens[tid * SEQ + t];
    } else if (t == 0) {
        if (tid < BATCH) tok_s[tid] = 0;
    } else {
        argmax_finalize(tid, pk, redk, tok_s);
    }
    stage_h(&hl[0][0], h_in, tid);
    __syncthreads();
    gru_core(blockIdx.x, tid, tok_s, &hl[0][0], h_out, Wih, Whh, bih, bhh, emb);
}

__global__ __launch_bounds__(256) void logits_fb(
    const float* __restrict__ h, const float* __restrict__ outW,
    const float* __restrict__ outb, float* __restrict__ out,
    int t, u64* __restrict__ pk)
{
    __shared__ __align__(16) float hl[BATCH][HLDS_W];
    const int tid = threadIdx.x;
    stage_h(&hl[0][0], h, tid);
    __syncthreads();
    logits_core(blockIdx.x, tid, &hl[0][0], outW, outb, out, t, pk);
}

__global__ __launch_bounds__(256) void copy_fb(const float* __restrict__ src,
                                               float* __restrict__ dst, int n) {
    int i = blockIdx.x * 256 + threadIdx.x;
    if (i < n) dst[i] = src[i];
}

__global__ __launch_bounds__(256) void softmax_fb(float* __restrict__ out) {
    __shared__ float redm[4];
    __shared__ float reds[4];
    softmax_row(out + (size_t)blockIdx.x * VOCAB, threadIdx.x, redm, reds);
}

extern "C" void kernel_launch(void* const* d_in, const int* in_sizes, int n_in,
                              void* d_out, int out_size, void* d_ws, size_t ws_size,
                              hipStream_t stream) {
    const int*   input    = (const int*)  d_in[0];
    const float* enc_emb  = (const float*)d_in[1];
    const float* enc_Wih  = (const float*)d_in[2];
    const float* enc_Whh  = (const float*)d_in[3];
    const float* enc_bih  = (const float*)d_in[4];
    const float* enc_bhh  = (const float*)d_in[5];
    const float* dec_emb  = (const float*)d_in[6];
    const float* dec_Wih  = (const float*)d_in[7];
    const float* dec_Whh  = (const float*)d_in[8];
    const float* dec_bih  = (const float*)d_in[9];
    const float* dec_bhh  = (const float*)d_in[10];
    const float* out_W    = (const float*)d_in[11];
    const float* out_b    = (const float*)d_in[12];

    float* out = (float*)d_out;
    float* ws  = (float*)d_ws;

    float* h0  = ws;                                  // 16384 f
    float* h1  = ws + BATCH * HDIM;                   // 16384 f
    u64*   pk  = (u64*)(ws + 2 * BATCH * HDIM);       // 8192 u64
    u32*   bar = (u32*)(ws + 4 * BATCH * HDIM);       // 1024 u32

    init_kernel<<<dim3(64), dim3(256), 0, stream>>>(h0, bar);

    void* args[] = {
        (void*)&input, (void*)&enc_emb, (void*)&enc_Wih, (void*)&enc_Whh,
        (void*)&enc_bih, (void*)&enc_bhh,
        (void*)&dec_emb, (void*)&dec_Wih, (void*)&dec_Whh, (void*)&dec_bih,
        (void*)&dec_bhh, (void*)&out_W, (void*)&out_b,
        (void*)&out, (void*)&h0, (void*)&h1, (void*)&pk, (void*)&bar
    };
    hipError_t rc = hipLaunchCooperativeKernel((void*)seq2seq_main,
                                               dim3(NBLK), dim3(NTHR),
                                               args, 0, stream);
    if (rc != hipSuccess) {
        // fallback: multi-kernel path (kernel boundaries provide the ordering)
        float* hb[2] = { h0, h1 };
        for (int t = 0; t < SEQ; ++t) {
            gru_step_fb<<<dim3(NGRU), dim3(256), 0, stream>>>(
                hb[t & 1], hb[(t + 1) & 1],
                enc_Wih, enc_Whh, enc_bih, enc_bhh, enc_emb, input, t, nullptr);
        }
        for (int t = 0; t < SEQ; ++t) {
            gru_step_fb<<<dim3(NGRU), dim3(256), 0, stream>>>(
                hb[t & 1], hb[(t + 1) & 1],
                dec_Wih, dec_Whh, dec_bih, dec_bhh, dec_emb, nullptr, t, pk);
            logits_fb<<<dim3(NBLK), dim3(256), 0, stream>>>(
                hb[(t + 1) & 1], out_W, out_b, out, t, pk);
        }
        copy_fb<<<dim3((BATCH * HDIM + 255) / 256), dim3(256), 0, stream>>>(
            h0, out + (size_t)BATCH * SEQ * VOCAB, BATCH * HDIM);
        softmax_fb<<<dim3(BATCH * SEQ), dim3(256), 0, stream>>>(out);
    }
}

// Round 6
// 14984.155 us; speedup vs baseline: 2.5396x; 1.0274x over previous
//
#include <hip/hip_runtime.h>

#define HDIM 512
#define BATCH 32
#define SEQ 128
#define VOCAB 16384
#define NBLK 256      // grid blocks (1 per CU)
#define NGRU 128      // blocks running the GRU phase (4 j's each)
#define NTHR 256
#define SLOTP 32      // u32s per barrier line (128 B)
#define HLDS_W 516    // padded LDS row width in floats (4-way instead of 32-way)

typedef unsigned long long u64;
typedef unsigned int u32;

// ---------- relaxed agent-scope (MALL-coherent, no L2 inv/wb) accessors ----------
static __device__ __forceinline__ u64 aload64(const u64* p) {
    return __hip_atomic_load(p, __ATOMIC_RELAXED, __HIP_MEMORY_SCOPE_AGENT);
}
static __device__ __forceinline__ void astore64(u64* p, u64 v) {
    __hip_atomic_store(p, v, __ATOMIC_RELAXED, __HIP_MEMORY_SCOPE_AGENT);
}
static __device__ __forceinline__ u32 aload32(const u32* p) {
    return __hip_atomic_load(p, __ATOMIC_RELAXED, __HIP_MEMORY_SCOPE_AGENT);
}
static __device__ __forceinline__ void astore32(u32* p, u32 v) {
    __hip_atomic_store(p, v, __ATOMIC_RELAXED, __HIP_MEMORY_SCOPE_AGENT);
}
static __device__ __forceinline__ void astore32f(float* p, float v) {
    __hip_atomic_store((u32*)p, __float_as_uint(v), __ATOMIC_RELAXED,
                       __HIP_MEMORY_SCOPE_AGENT);
}

static __device__ __forceinline__ float4 ld4(const float* p) {
    return *reinterpret_cast<const float4*>(p);
}
static __device__ __forceinline__ float dot4(float4 a, float4 b) {
    return a.x*b.x + a.y*b.y + a.z*b.z + a.w*b.w;
}
static __device__ __forceinline__ u32 ford(float f) {   // monotone float->u32
    u32 b = __float_as_uint(f);
    return b ^ ((b >> 31) ? 0xFFFFFFFFu : 0x80000000u);
}
static __device__ __forceinline__ u64 shfl_xor_u64(u64 x, int m) {
    int lo = __shfl_xor((int)(u32)x, m);
    int hi = __shfl_xor((int)(u32)(x >> 32), m);
    return ((u64)(u32)hi << 32) | (u32)lo;
}

// ---------- tree barrier: relaxed stores only, no RMW, <=32 readers per line ----
// Region layout: slots[256 lines] + go[8 lines].
// Arrival: block b stores `target` to its own slot (after vmcnt(0)).
// Detect: leader blocks 0..7 poll ALL nblk slots (distinct lines, read-only).
// Broadcast: leader g stores go[g]; block b polls go[b&7] (<=32 readers/line).
// All relaxed sc1 (MALL), so no L2 invalidate/writeback anywhere; producer-side
// vmcnt(0) + consumer in-order issue after poll-exit gives the data ordering
// (validated numerically in rounds 5: absmax unchanged at 0.0625).
static __device__ __forceinline__ void tbar(u32* base, u32 target,
                                            int blk, int tid, int nblk) {
    u32* slots = base;
    u32* go    = base + 256 * SLOTP;
    __syncthreads();
    asm volatile("s_waitcnt vmcnt(0)" ::: "memory");
    if (tid == 0)
        astore32(&slots[blk * SLOTP], target);
    if (blk < 8) {
        if (tid < 64) {
            const int per = nblk >> 6;   // slots per lane (2 or 4)
            int it = 0;
            for (;;) {
                bool ok = true;
                for (int k = 0; k < per; ++k)
                    ok &= (aload32(&slots[(tid * per + k) * SLOTP]) >= target);
                if (__ballot(ok) == ~0ull) break;
                if (++it > 16)     __builtin_amdgcn_s_sleep(4);
                else if (it > 2)   __builtin_amdgcn_s_sleep(1);
            }
            if (tid == 0) astore32(&go[blk * SLOTP], target);
        }
    }
    if (tid == 0) {
        const u32* g = &go[(blk & 7) * SLOTP];
        int it = 0;
        while (aload32(g) < target) {
            if (++it > 16)   __builtin_amdgcn_s_sleep(4);
            else if (it > 2) __builtin_amdgcn_s_sleep(1);
        }
    }
    __syncthreads();
    asm volatile("" ::: "memory");
}

// ---------- stage full h (32x512 f32, 64KB) into LDS via coalesced sc1 loads ----------
static __device__ __forceinline__ void stage_h(float* hlf, const float* hglob, int tid) {
    const u64* src = (const u64*)hglob;
    #pragma unroll
    for (int it = 0; it < 32; ++it) {
        int q = it * NTHR + tid;          // u64 index 0..8191
        int w = q * 2;                    // float index
        int b = w >> 9, k = w & 511;
        u64 v = aload64(src + q);
        *reinterpret_cast<u64*>(hlf + b * HLDS_W + k) = v;
    }
}

// ---------- GRU core: bit-identical arithmetic; h from LDS; h_out via sc1 ----------
static __device__ __forceinline__ void gru_core(
    int blk, int tid, const int* toks, const float* hlf, float* hout,
    const float* __restrict__ Wih, const float* __restrict__ Whh,
    const float* __restrict__ bih, const float* __restrict__ bhh,
    const float* __restrict__ emb)
{
    const int wave = tid >> 6;
    const int lane = tid & 63;
    const int kh   = lane >> 5;
    const int b    = lane & 31;
    const int j    = blk * 4 + wave;

    const int tok = toks[b];
    const float* xrow = emb + (size_t)tok * HDIM + kh * 256;
    const float* hrow = hlf + b * HLDS_W + kh * 256;
    const float* wir = Wih + (size_t)(0*HDIM + j) * HDIM + kh * 256;
    const float* wiz = Wih + (size_t)(1*HDIM + j) * HDIM + kh * 256;
    const float* win = Wih + (size_t)(2*HDIM + j) * HDIM + kh * 256;
    const float* whr = Whh + (size_t)(0*HDIM + j) * HDIM + kh * 256;
    const float* whz = Whh + (size_t)(1*HDIM + j) * HDIM + kh * 256;
    const float* whn = Whh + (size_t)(2*HDIM + j) * HDIM + kh * 256;

    float pr = 0.f, pz = 0.f, pxn = 0.f, phn = 0.f;
    #pragma unroll 4
    for (int k4 = 0; k4 < 64; ++k4) {
        float4 x4 = ld4(xrow + k4*4);
        float4 h4 = ld4(hrow + k4*4);
        pr  += dot4(x4, ld4(wir + k4*4)) + dot4(h4, ld4(whr + k4*4));
        pz  += dot4(x4, ld4(wiz + k4*4)) + dot4(h4, ld4(whz + k4*4));
        pxn += dot4(x4, ld4(win + k4*4));
        phn += dot4(h4, ld4(whn + k4*4));
    }
    pr  += __shfl_xor(pr, 32);
    pz  += __shfl_xor(pz, 32);
    pxn += __shfl_xor(pxn, 32);
    phn += __shfl_xor(phn, 32);

    if (kh == 0) {
        float r = 1.f / (1.f + expf(-(pr + bih[j]      + bhh[j])));
        float z = 1.f / (1.f + expf(-(pz + bih[HDIM+j] + bhh[HDIM+j])));
        float n = tanhf(pxn + bih[2*HDIM+j] + r * (phn + bhh[2*HDIM+j]));
        float hprev = hlf[b * HLDS_W + j];
        astore32f(hout + b * HDIM + j, (1.f - z) * n + z * hprev);
    }
}

// ---------- logits core: per-thread 4 k-quarter accumulators (exact order
// match with the part[4]-combine of rounds 1-4), h from LDS (uniform reads) ----------
static __device__ __forceinline__ void logits_core(
    int blk, int tid, const float* hlf,
    const float* __restrict__ outW, const float* __restrict__ outb,
    float* __restrict__ out, int t, u64* pk)
{
    const int vloc = tid & 63;
    const int bq   = tid >> 6;
    const int v    = blk * 64 + vloc;
    const float* wrow = outW + (size_t)v * HDIM;

    float acc[4][8];
    #pragma unroll
    for (int q = 0; q < 4; ++q)
        #pragma unroll
        for (int i = 0; i < 8; ++i) acc[q][i] = 0.f;

    #pragma unroll
    for (int q = 0; q < 4; ++q) {
        for (int k4 = 0; k4 < 32; ++k4) {
            float4 w4 = ld4(wrow + q*128 + k4*4);
            #pragma unroll
            for (int i = 0; i < 8; ++i) {
                float4 h4 = ld4(hlf + (bq*8 + i) * HLDS_W + q*128 + k4*4);
                acc[q][i] += dot4(w4, h4);
            }
        }
    }

    const float vbias = outb[v];
    #pragma unroll
    for (int i = 0; i < 8; ++i) {
        const int b = bq*8 + i;
        float s = ((acc[0][i] + acc[1][i]) + acc[2][i]) + acc[3][i] + vbias;
        out[(size_t)b * (SEQ * VOCAB) + (size_t)t * VOCAB + v] = s;

        u64 key = ((u64)ford(s) << 32) | (u32)(~(u32)v);
        #pragma unroll
        for (int d = 1; d < 64; d <<= 1) {
            u64 o = shfl_xor_u64(key, d);
            if (o > key) key = o;
        }
        if (vloc == 0) astore64(pk + b * NBLK + blk, key);
    }
}

// ---------- argmax finalize (tokens from pk partials), coalesced sc1 reads ----------
static __device__ __forceinline__ void argmax_finalize(
    int tid, const u64* pk, u64 (*redk)[8], int* tok_s)
{
    const int fb = tid >> 3, kc = tid & 7;
    const u64* p = pk + fb * NBLK;
    u64 best = aload64(p + kc);
    #pragma unroll 4
    for (int k = 1; k < 32; ++k) {
        u64 x = aload64(p + kc + k * 8);
        if (x > best) best = x;
    }
    redk[fb][kc] = best;
    __syncthreads();
    if (tid < BATCH) {
        u64 bb = redk[tid][0];
        #pragma unroll
        for (int c = 1; c < 8; ++c) { u64 x = redk[tid][c]; if (x > bb) bb = x; }
        tok_s[tid] = (int)(~(u32)bb);
    }
}

// ---------- log_softmax over one 16384-row ----------
static __device__ __forceinline__ void softmax_row(float* p, int tid,
                                                   float* redm, float* reds) {
    float4 vals[16];
    float m = -3.4e38f;
    #pragma unroll
    for (int i = 0; i < 16; ++i) {
        vals[i] = ld4(p + (i * 256 + tid) * 4);
        m = fmaxf(m, fmaxf(fmaxf(vals[i].x, vals[i].y), fmaxf(vals[i].z, vals[i].w)));
    }
    #pragma unroll
    for (int d = 1; d < 64; d <<= 1) m = fmaxf(m, __shfl_xor(m, d));
    if ((tid & 63) == 0) redm[tid >> 6] = m;
    __syncthreads();
    m = fmaxf(fmaxf(redm[0], redm[1]), fmaxf(redm[2], redm[3]));

    float s = 0.f;
    #pragma unroll
    for (int i = 0; i < 16; ++i) {
        s += expf(vals[i].x - m) + expf(vals[i].y - m)
           + expf(vals[i].z - m) + expf(vals[i].w - m);
    }
    #pragma unroll
    for (int d = 1; d < 64; d <<= 1) s += __shfl_xor(s, d);
    if ((tid & 63) == 0) reds[tid >> 6] = s;
    __syncthreads();
    s = reds[0] + reds[1] + reds[2] + reds[3];

    const float lg = m + logf(s);
    #pragma unroll
    for (int i = 0; i < 16; ++i) {
        float4 r;
        r.x = vals[i].x - lg; r.y = vals[i].y - lg;
        r.z = vals[i].z - lg; r.w = vals[i].w - lg;
        *reinterpret_cast<float4*>(p + (i * 256 + tid) * 4) = r;
    }
    __syncthreads();
}

// ==================== persistent cooperative kernel ====================
__global__ __launch_bounds__(NTHR, 1) void seq2seq_main(
    const int* __restrict__ input,
    const float* __restrict__ enc_emb, const float* __restrict__ enc_Wih,
    const float* __restrict__ enc_Whh, const float* __restrict__ enc_bih,
    const float* __restrict__ enc_bhh,
    const float* __restrict__ dec_emb, const float* __restrict__ dec_Wih,
    const float* __restrict__ dec_Whh, const float* __restrict__ dec_bih,
    const float* __restrict__ dec_bhh,
    const float* __restrict__ out_W, const float* __restrict__ out_b,
    float* __restrict__ out, float* h0, float* h1, u64* pk, u32* bar)
{
    __shared__ __align__(16) float hl[BATCH][HLDS_W];   // 66048 B
    __shared__ int tok_s[BATCH];
    __shared__ u64 redk[BATCH][8];
    __shared__ float redm[4];
    __shared__ float reds[4];

    const int tid = threadIdx.x;
    const int blk = blockIdx.x;
    float* hlf = &hl[0][0];

    u32* barEnc = bar;                     // slots[256]+go[8] lines
    u32* barDec = bar + 264 * SLOTP;       // slots[256]+go[8] lines

    // ---- encoder: 128 steps, blocks < NGRU (leaders 0..7 participate) ----
    if (blk < NGRU) {
        for (int t = 0; t < SEQ; ++t) {
            float* hin  = (t & 1) ? h1 : h0;
            float* hout = (t & 1) ? h0 : h1;
            if (tid < BATCH) tok_s[tid] = input[tid * SEQ + t];
            stage_h(hlf, hin, tid);
            __syncthreads();
            gru_core(blk, tid, tok_s, hlf, hout,
                     enc_Wih, enc_Whh, enc_bih, enc_bhh, enc_emb);
            tbar(barEnc, (u32)(t + 1), blk, tid, NGRU);
        }
    }

    // ---- decoder: 128 steps; shared region, epochs 2t+1 (A) / 2t+2 (B) ----
    for (int t = 0; t < SEQ; ++t) {
        float* hin  = (t & 1) ? h1 : h0;
        float* hout = (t & 1) ? h0 : h1;

        if (blk < NGRU) {
            if (t == 0) {
                if (tid < BATCH) tok_s[tid] = 0;   // SOS
                __syncthreads();
            } else {
                argmax_finalize(tid, pk, redk, tok_s);   // has internal sync
            }
            stage_h(hlf, hin, tid);
            __syncthreads();
            gru_core(blk, tid, tok_s, hlf, hout,
                     dec_Wih, dec_Whh, dec_bih, dec_bhh, dec_emb);
        }
        tbar(barDec, (u32)(2 * t + 1), blk, tid, NBLK);   // h_out ready

        stage_h(hlf, hout, tid);
        __syncthreads();
        logits_core(blk, tid, hlf, out_W, out_b, out, t, pk);
        tbar(barDec, (u32)(2 * t + 2), blk, tid, NBLK);   // pk ready
    }

    // ---- flush dirty logits (one-time) so plain softmax loads see them ----
    __threadfence();
    tbar(barDec, (u32)(2 * SEQ + 1), blk, tid, NBLK);

    // ---- folded log_softmax: 16 rows per block ----
    for (int i = 0; i < 16; ++i)
        softmax_row(out + (size_t)(blk * 16 + i) * VOCAB, tid, redm, reds);

    // ---- final decoder hidden (h0 after t=127) -> out tail ----
    if (blk < 16) {
        const u64* s = (const u64*)h0;
        u64* d = (u64*)(out + (size_t)BATCH * SEQ * VOCAB);
        #pragma unroll
        for (int k = 0; k < 2; ++k) {
            int idx = blk * 512 + k * 256 + tid;
            d[idx] = aload64(s + idx);
        }
    }
}

// ---- init: zero h0 + barrier area (ws is not re-poisoned between replays) ----
#define BAR_U32 (2 * 264 * SLOTP)
__global__ __launch_bounds__(256) void init_kernel(float* __restrict__ h0,
                                                   u32* __restrict__ bar) {
    int i = blockIdx.x * 256 + threadIdx.x;
    if (i < BATCH * HDIM) h0[i] = 0.f;
    if (i < BAR_U32) bar[i] = 0;
}

// ==================== fallback multi-kernel path ====================
__global__ __launch_bounds__(256) void gru_step_fb(
    const float* __restrict__ h_in, float* __restrict__ h_out,
    const float* __restrict__ Wih, const float* __restrict__ Whh,
    const float* __restrict__ bih, const float* __restrict__ bhh,
    const float* __restrict__ emb,
    const int* __restrict__ enc_tokens, int t, const u64* __restrict__ pk)
{
    __shared__ __align__(16) float hl[BATCH][HLDS_W];
    __shared__ int tok_s[BATCH];
    __shared__ u64 redk[BATCH][8];
    const int tid = threadIdx.x;

    if (enc_tokens != nullptr) {
        if (tid < BATCH) tok_s[tid] = enc_tokens[tid * SEQ + t];
    } else if (t == 0) {
        if (tid < BATCH) tok_s[tid] = 0;
    } else {
        argmax_finalize(tid, pk, redk, tok_s);
    }
    stage_h(&hl[0][0], h_in, tid);
    __syncthreads();
    gru_core(blockIdx.x, tid, tok_s, &hl[0][0], h_out, Wih, Whh, bih, bhh, emb);
}

__global__ __launch_bounds__(256) void logits_fb(
    const float* __restrict__ h, const float* __restrict__ outW,
    const float* __restrict__ outb, float* __restrict__ out,
    int t, u64* __restrict__ pk)
{
    __shared__ __align__(16) float hl[BATCH][HLDS_W];
    const int tid = threadIdx.x;
    stage_h(&hl[0][0], h, tid);
    __syncthreads();
    logits_core(blockIdx.x, tid, &hl[0][0], outW, outb, out, t, pk);
}

__global__ __launch_bounds__(256) void copy_fb(const float* __restrict__ src,
                                               float* __restrict__ dst, int n) {
    int i = blockIdx.x * 256 + threadIdx.x;
    if (i < n) dst[i] = src[i];
}

__global__ __launch_bounds__(256) void softmax_fb(float* __restrict__ out) {
    __shared__ float redm[4];
    __shared__ float reds[4];
    softmax_row(out + (size_t)blockIdx.x * VOCAB, threadIdx.x, redm, reds);
}

extern "C" void kernel_launch(void* const* d_in, const int* in_sizes, int n_in,
                              void* d_out, int out_size, void* d_ws, size_t ws_size,
                              hipStream_t stream) {
    const int*   input    = (const int*)  d_in[0];
    const float* enc_emb  = (const float*)d_in[1];
    const float* enc_Wih  = (const float*)d_in[2];
    const float* enc_Whh  = (const float*)d_in[3];
    const float* enc_bih  = (const float*)d_in[4];
    const float* enc_bhh  = (const float*)d_in[5];
    const float* dec_emb  = (const float*)d_in[6];
    const float* dec_Wih  = (const float*)d_in[7];
    const float* dec_Whh  = (const float*)d_in[8];
    const float* dec_bih  = (const float*)d_in[9];
    const float* dec_bhh  = (const float*)d_in[10];
    const float* out_W    = (const float*)d_in[11];
    const float* out_b    = (const float*)d_in[12];

    float* out = (float*)d_out;
    float* ws  = (float*)d_ws;

    float* h0  = ws;                                  // 16384 f
    float* h1  = ws + BATCH * HDIM;                   // 16384 f
    u64*   pk  = (u64*)(ws + 2 * BATCH * HDIM);       // 8192 u64
    u32*   bar = (u32*)(ws + 4 * BATCH * HDIM);       // 16896 u32

    init_kernel<<<dim3(128), dim3(256), 0, stream>>>(h0, bar);

    void* args[] = {
        (void*)&input, (void*)&enc_emb, (void*)&enc_Wih, (void*)&enc_Whh,
        (void*)&enc_bih, (void*)&enc_bhh,
        (void*)&dec_emb, (void*)&dec_Wih, (void*)&dec_Whh, (void*)&dec_bih,
        (void*)&dec_bhh, (void*)&out_W, (void*)&out_b,
        (void*)&out, (void*)&h0, (void*)&h1, (void*)&pk, (void*)&bar
    };
    hipError_t rc = hipLaunchCooperativeKernel((void*)seq2seq_main,
                                               dim3(NBLK), dim3(NTHR),
                                               args, 0, stream);
    if (rc != hipSuccess) {
        // fallback: multi-kernel path (kernel boundaries provide the ordering)
        float* hb[2] = { h0, h1 };
        for (int t = 0; t < SEQ; ++t) {
            gru_step_fb<<<dim3(NGRU), dim3(256), 0, stream>>>(
                hb[t & 1], hb[(t + 1) & 1],
                enc_Wih, enc_Whh, enc_bih, enc_bhh, enc_emb, input, t, nullptr);
        }
        for (int t = 0; t < SEQ; ++t) {
            gru_step_fb<<<dim3(NGRU), dim3(256), 0, stream>>>(
                hb[t & 1], hb[(t + 1) & 1],
                dec_Wih, dec_Whh, dec_bih, dec_bhh, dec_emb, nullptr, t, pk);
            logits_fb<<<dim3(NBLK), dim3(256), 0, stream>>>(
                hb[(t + 1) & 1], out_W, out_b, out, t, pk);
        }
        copy_fb<<<dim3((BATCH * HDIM + 255) / 256), dim3(256), 0, stream>>>(
            h0, out + (size_t)BATCH * SEQ * VOCAB, BATCH * HDIM);
        softmax_fb<<<dim3(BATCH * SEQ), dim3(256), 0, stream>>>(out);
    }
}

// Round 8
// 9804.569 us; speedup vs baseline: 3.8812x; 1.5283x over previous
//
#include <hip/hip_runtime.h>

#define HDIM 512
#define BATCH 32
#define SEQ 128
#define VOCAB 16384
#define NBLK 256
#define NGRU 128
#define NTHR 256
#define SLOTP 32          // u32s per 128B line
#define HLDS_W 516        // padded LDS row (4-way conflicts only)

typedef unsigned long long u64;
typedef unsigned int u32;

// ---------------- MALL agent-relaxed accessors (validated R5/R6) ----------------
static __device__ __forceinline__ u64 aload64(const u64* p) {
    return __hip_atomic_load(p, __ATOMIC_RELAXED, __HIP_MEMORY_SCOPE_AGENT);
}
static __device__ __forceinline__ void astore64(u64* p, u64 v) {
    __hip_atomic_store(p, v, __ATOMIC_RELAXED, __HIP_MEMORY_SCOPE_AGENT);
}
static __device__ __forceinline__ u32 aload32(const u32* p) {
    return __hip_atomic_load(p, __ATOMIC_RELAXED, __HIP_MEMORY_SCOPE_AGENT);
}
static __device__ __forceinline__ void astore32(u32* p, u32 v) {
    __hip_atomic_store(p, v, __ATOMIC_RELAXED, __HIP_MEMORY_SCOPE_AGENT);
}
static __device__ __forceinline__ void astore32f(float* p, float v) {
    __hip_atomic_store((u32*)p, __float_as_uint(v), __ATOMIC_RELAXED,
                       __HIP_MEMORY_SCOPE_AGENT);
}

static __device__ __forceinline__ float4 ld4(const float* p) {
    return *reinterpret_cast<const float4*>(p);
}
static __device__ __forceinline__ float dot4(float4 a, float4 b) {
    return a.x*b.x + a.y*b.y + a.z*b.z + a.w*b.w;
}
static __device__ __forceinline__ u32 ford(float f) {   // monotone float->u32
    u32 b = __float_as_uint(f);
    return b ^ ((b >> 31) ? 0xFFFFFFFFu : 0x80000000u);
}
static __device__ __forceinline__ u64 shfl_xor_u64(u64 x, int m) {
    int lo = __shfl_xor((int)(u32)x, m);
    int hi = __shfl_xor((int)(u32)(x >> 32), m);
    return ((u64)(u32)hi << 32) | (u32)lo;
}

// ---- poll N per-block flag lines (N=128: per=2, N=256: per=4), read-only ----
// Consumers poll producers' own lines directly; no broadcast hop, no RMW.
// Monotonic epochs; escalating s_sleep keeps far-from-target polls cheap.
static __device__ __forceinline__ void pollN(const u32* slots, u32 target,
                                             int tid, int per) {
    if (tid < 64) {
        int it = 0;
        for (;;) {
            bool ok = true;
            #pragma unroll
            for (int k = 0; k < 4; ++k)
                if (k < per)
                    ok &= (aload32(&slots[(tid * per + k) * SLOTP]) >= target);
            if (__ballot(ok) == ~0ull) break;
            if (it > 64)      __builtin_amdgcn_s_sleep(16);
            else if (it > 8)  __builtin_amdgcn_s_sleep(2);
            ++it;
        }
    }
    __syncthreads();
    asm volatile("" ::: "memory");
}

// ---- stage 64KB h from MALL into LDS: wide non-atomic sc1 loads (agent view) ----
// 16B/lane, bulk-read path (not the atomic pipe) -- the R8 fix.
static __device__ __forceinline__ void stage_wide(float* hlf, const float* hsrc, int tid) {
    #pragma unroll
    for (int g = 0; g < 2; ++g) {
        float4 v[8];
        #pragma unroll
        for (int k = 0; k < 8; ++k) {
            int q = (g * 8 + k) * NTHR + tid;            // float4 index
            asm volatile("global_load_dwordx4 %0, %1, off sc1"
                         : "=v"(v[k]) : "v"(hsrc + q * 4));
        }
        asm volatile("s_waitcnt vmcnt(0)" ::: "memory");
        __builtin_amdgcn_sched_barrier(0);
        #pragma unroll
        for (int k = 0; k < 8; ++k) {
            int q = (g * 8 + k) * NTHR + tid;
            int w = q * 4;
            *reinterpret_cast<float4*>(hlf + (w >> 9) * HLDS_W + (w & 511)) = v[k];
        }
    }
}

// ---- stage via relaxed-atomic u64 (fallback kernels only; R6-validated) ----
static __device__ __forceinline__ void stage_h(float* hlf, const float* hglob, int tid) {
    const u64* src = (const u64*)hglob;
    #pragma unroll
    for (int it = 0; it < 32; ++it) {
        int q = it * NTHR + tid;
        int w = q * 2;
        u64 v = aload64(src + q);
        *reinterpret_cast<u64*>(hlf + (w >> 9) * HLDS_W + (w & 511)) = v;
    }
}

// ---- GRU core: bit-identical arithmetic since round 1 ----
static __device__ __forceinline__ void gru_core(
    int blk, int tid, const int* toks, const float* hlf, float* hout,
    const float* __restrict__ Wih, const float* __restrict__ Whh,
    const float* __restrict__ bih, const float* __restrict__ bhh,
    const float* __restrict__ emb)
{
    const int wave = tid >> 6;
    const int lane = tid & 63;
    const int kh   = lane >> 5;
    const int b    = lane & 31;
    const int j    = blk * 4 + wave;

    const int tok = toks[b];
    const float* xrow = emb + (size_t)tok * HDIM + kh * 256;
    const float* hrow = hlf + b * HLDS_W + kh * 256;
    const float* wir = Wih + (size_t)(0*HDIM + j) * HDIM + kh * 256;
    const float* wiz = Wih + (size_t)(1*HDIM + j) * HDIM + kh * 256;
    const float* win = Wih + (size_t)(2*HDIM + j) * HDIM + kh * 256;
    const float* whr = Whh + (size_t)(0*HDIM + j) * HDIM + kh * 256;
    const float* whz = Whh + (size_t)(1*HDIM + j) * HDIM + kh * 256;
    const float* whn = Whh + (size_t)(2*HDIM + j) * HDIM + kh * 256;

    float pr = 0.f, pz = 0.f, pxn = 0.f, phn = 0.f;
    #pragma unroll 4
    for (int k4 = 0; k4 < 64; ++k4) {
        float4 x4 = ld4(xrow + k4*4);
        float4 h4 = ld4(hrow + k4*4);
        pr  += dot4(x4, ld4(wir + k4*4)) + dot4(h4, ld4(whr + k4*4));
        pz  += dot4(x4, ld4(wiz + k4*4)) + dot4(h4, ld4(whz + k4*4));
        pxn += dot4(x4, ld4(win + k4*4));
        phn += dot4(h4, ld4(whn + k4*4));
    }
    pr  += __shfl_xor(pr, 32);
    pz  += __shfl_xor(pz, 32);
    pxn += __shfl_xor(pxn, 32);
    phn += __shfl_xor(phn, 32);

    if (kh == 0) {
        float r = 1.f / (1.f + expf(-(pr + bih[j]      + bhh[j])));
        float z = 1.f / (1.f + expf(-(pz + bih[HDIM+j] + bhh[HDIM+j])));
        float n = tanhf(pxn + bih[2*HDIM+j] + r * (phn + bhh[2*HDIM+j]));
        float hprev = hlf[b * HLDS_W + j];
        astore32f(hout + b * HDIM + j, (1.f - z) * n + z * hprev);
    }
}

// ---- logits core: exact k-quarter summation order of rounds 1-6 ----
static __device__ __forceinline__ void logits_core(
    int blk, int tid, const float* hlf,
    const float* __restrict__ outW, const float* __restrict__ outb,
    float* __restrict__ out, int t, u64* pk)
{
    const int vloc = tid & 63;
    const int bq   = tid >> 6;
    const int v    = blk * 64 + vloc;
    const float* wrow = outW + (size_t)v * HDIM;

    float acc[4][8];
    #pragma unroll
    for (int q = 0; q < 4; ++q)
        #pragma unroll
        for (int i = 0; i < 8; ++i) acc[q][i] = 0.f;

    #pragma unroll
    for (int q = 0; q < 4; ++q) {
        for (int k4 = 0; k4 < 32; ++k4) {
            float4 w4 = ld4(wrow + q*128 + k4*4);
            #pragma unroll
            for (int i = 0; i < 8; ++i) {
                float4 h4 = ld4(hlf + (bq*8 + i) * HLDS_W + q*128 + k4*4);
                acc[q][i] += dot4(w4, h4);
            }
        }
    }
    const float vbias = outb[v];
    #pragma unroll
    for (int i = 0; i < 8; ++i) {
        const int b = bq*8 + i;
        float s = ((acc[0][i] + acc[1][i]) + acc[2][i]) + acc[3][i] + vbias;
        __builtin_nontemporal_store(s, &out[(size_t)b*(SEQ*VOCAB) + (size_t)t*VOCAB + v]);
        u64 key = ((u64)ford(s) << 32) | (u32)(~(u32)v);
        #pragma unroll
        for (int d = 1; d < 64; d <<= 1) {
            u64 o = shfl_xor_u64(key, d);
            if (o > key) key = o;
        }
        if (vloc == 0) astore64(pk + b * NBLK + blk, key);
    }
}

// ---- argmax finalize (256 pk partials -> 32 tokens) ----
static __device__ __forceinline__ void argmax_finalize(
    int tid, const u64* pk, u64 (*redk)[8], int* tok_s)
{
    const int fb = tid >> 3, kc = tid & 7;
    const u64* p = pk + fb * NBLK;
    u64 best = aload64(p + kc);
    #pragma unroll 4
    for (int k = 1; k < 32; ++k) {
        u64 x = aload64(p + kc + k * 8);
        if (x > best) best = x;
    }
    redk[fb][kc] = best;
    __syncthreads();
    if (tid < BATCH) {
        u64 bb = redk[tid][0];
        #pragma unroll
        for (int c = 1; c < 8; ++c) { u64 x = redk[tid][c]; if (x > bb) bb = x; }
        tok_s[tid] = (int)(~(u32)bb);
    }
}

// ---- log_softmax row ----
static __device__ __forceinline__ void softmax_row(float* p, int tid,
                                                   float* redm, float* reds) {
    float4 vals[16];
    float m = -3.4e38f;
    #pragma unroll
    for (int i = 0; i < 16; ++i) {
        vals[i] = ld4(p + (i * 256 + tid) * 4);
        m = fmaxf(m, fmaxf(fmaxf(vals[i].x, vals[i].y), fmaxf(vals[i].z, vals[i].w)));
    }
    #pragma unroll
    for (int d = 1; d < 64; d <<= 1) m = fmaxf(m, __shfl_xor(m, d));
    if ((tid & 63) == 0) redm[tid >> 6] = m;
    __syncthreads();
    m = fmaxf(fmaxf(redm[0], redm[1]), fmaxf(redm[2], redm[3]));
    float s = 0.f;
    #pragma unroll
    for (int i = 0; i < 16; ++i) {
        s += expf(vals[i].x - m) + expf(vals[i].y - m)
           + expf(vals[i].z - m) + expf(vals[i].w - m);
    }
    #pragma unroll
    for (int d = 1; d < 64; d <<= 1) s += __shfl_xor(s, d);
    if ((tid & 63) == 0) reds[tid >> 6] = s;
    __syncthreads();
    s = reds[0] + reds[1] + reds[2] + reds[3];
    const float lg = m + logf(s);
    #pragma unroll
    for (int i = 0; i < 16; ++i) {
        float4 r;
        r.x = vals[i].x - lg; r.y = vals[i].y - lg;
        r.z = vals[i].z - lg; r.w = vals[i].w - lg;
        *reinterpret_cast<float4*>(p + (i * 256 + tid) * 4) = r;
    }
    __syncthreads();
}

// ==================== persistent cooperative kernel ====================
__global__ __launch_bounds__(NTHR, 1) void seq2seq_main(
    const int* __restrict__ input,
    const float* __restrict__ enc_emb, const float* __restrict__ enc_Wih,
    const float* __restrict__ enc_Whh, const float* __restrict__ enc_bih,
    const float* __restrict__ enc_bhh,
    const float* __restrict__ dec_emb, const float* __restrict__ dec_Wih,
    const float* __restrict__ dec_Whh, const float* __restrict__ dec_bih,
    const float* __restrict__ dec_bhh,
    const float* __restrict__ out_W, const float* __restrict__ out_b,
    float* __restrict__ out, float* hglob, u64* pk,
    u32* hslot, u32* pkslot)
{
    __shared__ __align__(16) float hl[BATCH][HLDS_W];   // 66048 B
    __shared__ int tok_s[BATCH];
    __shared__ u64 redk[BATCH][8];

    const int tid = threadIdx.x;
    const int blk = blockIdx.x;
    float* hlf = &hl[0][0];

    // hlf = h(0) = 0 (used by encoder step 0)
    for (int i = tid; i < BATCH * HLDS_W; i += NTHR) hlf[i] = 0.f;
    __syncthreads();

    // ---------------- encoder: 128 steps (blocks 0..127 only) ----------------
    if (blk < NGRU) {
        for (int t = 0; t < SEQ; ++t) {
            float* hgo = hglob + ((t + 1) & 1) * (BATCH * HDIM);
            if (tid < BATCH) tok_s[tid] = input[tid * SEQ + t];
            __syncthreads();
            gru_core(blk, tid, tok_s, hlf, hgo,
                     enc_Wih, enc_Whh, enc_bih, enc_bhh, enc_emb);
            __syncthreads();                          // drains all waves' h stores
            if (tid == 0) astore32(&hslot[blk * SLOTP], (u32)(t + 1));
            pollN(hslot, (u32)(t + 1), tid, 2);       // h(t+1) @ MALL
            stage_wide(hlf, hgo, tid);                // hlf <- h(t+1)
            __syncthreads();
        }
    }

    // ---------------- decoder: 128 steps ----------------
    for (int t = 0; t < SEQ; ++t) {
        float* hgo = hglob + ((t + 1) & 1) * (BATCH * HDIM);

        if (blk < NGRU) {
            if (t == 0) {
                if (tid < BATCH) tok_s[tid] = 0;      // SOS
                __syncthreads();
            } else {
                pollN(pkslot, (u32)t, tid, 4);        // all 256 logits(t-1) done
                argmax_finalize(tid, pk, redk, tok_s);
                __syncthreads();
            }
            // hlf holds h(t) (staged last step); compute h(t+1)
            gru_core(blk, tid, tok_s, hlf, hgo,
                     dec_Wih, dec_Whh, dec_bih, dec_bhh, dec_emb);
            __syncthreads();                          // drain h stores
            if (tid == 0) astore32(&hslot[blk * SLOTP], (u32)(SEQ + t + 1));
        }

        pollN(hslot, (u32)(SEQ + t + 1), tid, 2);     // h(t+1) @ MALL
        stage_wide(hlf, hgo, tid);                    // hlf <- h(t+1)
        __syncthreads();
        logits_core(blk, tid, hlf, out_W, out_b, out, t, pk);
        __syncthreads();                              // drain NT + pk stores
        if (tid == 0) astore32(&pkslot[blk * SLOTP], (u32)(t + 1));
    }

    // ---- final decoder hidden: hlf holds h(dec,128) on every block ----
    if (blk < 16) {
        const int idx = blk * 1024 + tid * 4;
        const int b = idx >> 9, j = idx & 511;
        *reinterpret_cast<float4*>(out + (size_t)BATCH * SEQ * VOCAB + idx) =
            *reinterpret_cast<const float4*>(&hl[b][j]);
    }
}

// ---- init: zero h0 + flag lines (ws not re-poisoned between replays) ----
#define SLOT_U32 ((128 + 256) * SLOTP)
__global__ __launch_bounds__(256) void init_kernel(float* __restrict__ h0,
                                                   u32* __restrict__ slots) {
    int i = blockIdx.x * 256 + threadIdx.x;
    if (i < BATCH * HDIM) h0[i] = 0.f;
    if (i < SLOT_U32) slots[i] = 0;
}

// ==================== fallback multi-kernel path (R6-proven) ====================
__global__ __launch_bounds__(256) void gru_step_fb(
    const float* __restrict__ h_in, float* __restrict__ h_out,
    const float* __restrict__ Wih, const float* __restrict__ Whh,
    const float* __restrict__ bih, const float* __restrict__ bhh,
    const float* __restrict__ emb,
    const int* __restrict__ enc_tokens, int t, const u64* __restrict__ pk)
{
    __shared__ __align__(16) float hlt[BATCH][HLDS_W];
    __shared__ int tok_s[BATCH];
    __shared__ u64 redk[BATCH][8];
    const int tid = threadIdx.x;

    if (enc_tokens != nullptr) {
        if (tid < BATCH) tok_s[tid] = enc_tokens[tid * SEQ + t];
    } else if (t == 0) {
        if (tid < BATCH) tok_s[tid] = 0;
    } else {
        argmax_finalize(tid, pk, redk, tok_s);
    }
    stage_h(&hlt[0][0], h_in, tid);
    __syncthreads();
    gru_core(blockIdx.x, tid, tok_s, &hlt[0][0], h_out, Wih, Whh, bih, bhh, emb);
}

__global__ __launch_bounds__(256) void logits_fb(
    const float* __restrict__ h, const float* __restrict__ outW,
    const float* __restrict__ outb, float* __restrict__ out,
    int t, u64* __restrict__ pk)
{
    __shared__ __align__(16) float hlt[BATCH][HLDS_W];
    const int tid = threadIdx.x;
    stage_h(&hlt[0][0], h, tid);
    __syncthreads();
    logits_core(blockIdx.x, tid, &hlt[0][0], outW, outb, out, t, pk);
}

__global__ __launch_bounds__(256) void copy_fb(const float* __restrict__ src,
                                               float* __restrict__ dst, int n) {
    int i = blockIdx.x * 256 + threadIdx.x;
    if (i < n) dst[i] = src[i];
}

__global__ __launch_bounds__(256) void softmax_kernel(float* __restrict__ out) {
    __shared__ float redm[4];
    __shared__ float reds[4];
    softmax_row(out + (size_t)blockIdx.x * VOCAB, threadIdx.x, redm, reds);
}

extern "C" void kernel_launch(void* const* d_in, const int* in_sizes, int n_in,
                              void* d_out, int out_size, void* d_ws, size_t ws_size,
                              hipStream_t stream) {
    const int*   input    = (const int*)  d_in[0];
    const float* enc_emb  = (const float*)d_in[1];
    const float* enc_Wih  = (const float*)d_in[2];
    const float* enc_Whh  = (const float*)d_in[3];
    const float* enc_bih  = (const float*)d_in[4];
    const float* enc_bhh  = (const float*)d_in[5];
    const float* dec_emb  = (const float*)d_in[6];
    const float* dec_Wih  = (const float*)d_in[7];
    const float* dec_Whh  = (const float*)d_in[8];
    const float* dec_bih  = (const float*)d_in[9];
    const float* dec_bhh  = (const float*)d_in[10];
    const float* out_W    = (const float*)d_in[11];
    const float* out_b    = (const float*)d_in[12];

    float* out = (float*)d_out;
    char*  ws  = (char*)d_ws;

    float* hglob  = (float*)ws;                      // 2*16384 f = 131072 B
    u64*   pk     = (u64*)(ws + 131072);             // 8192 u64 = 65536 B
    u32*   hslot  = (u32*)(ws + 196608);             // 128 lines = 16384 B
    u32*   pkslot = (u32*)(ws + 212992);             // 256 lines = 32768 B

    init_kernel<<<dim3(64), dim3(256), 0, stream>>>(hglob, hslot);

    void* args[] = {
        (void*)&input, (void*)&enc_emb, (void*)&enc_Wih, (void*)&enc_Whh,
        (void*)&enc_bih, (void*)&enc_bhh,
        (void*)&dec_emb, (void*)&dec_Wih, (void*)&dec_Whh, (void*)&dec_bih,
        (void*)&dec_bhh, (void*)&out_W, (void*)&out_b,
        (void*)&out, (void*)&hglob, (void*)&pk,
        (void*)&hslot, (void*)&pkslot
    };
    hipError_t rc = hipLaunchCooperativeKernel((void*)seq2seq_main,
                                               dim3(NBLK), dim3(NTHR),
                                               args, 0, stream);
    if (rc != hipSuccess) {
        // fallback: multi-kernel path (kernel boundaries provide ordering)
        float* hb[2] = { hglob, hglob + BATCH * HDIM };
        for (int t = 0; t < SEQ; ++t) {
            gru_step_fb<<<dim3(NGRU), dim3(256), 0, stream>>>(
                hb[t & 1], hb[(t + 1) & 1],
                enc_Wih, enc_Whh, enc_bih, enc_bhh, enc_emb, input, t, nullptr);
        }
        for (int t = 0; t < SEQ; ++t) {
            gru_step_fb<<<dim3(NGRU), dim3(256), 0, stream>>>(
                hb[t & 1], hb[(t + 1) & 1],
                dec_Wih, dec_Whh, dec_bih, dec_bhh, dec_emb, nullptr, t, pk);
            logits_fb<<<dim3(NBLK), dim3(256), 0, stream>>>(
                hb[(t + 1) & 1], out_W, out_b, out, t, pk);
        }
        copy_fb<<<dim3((BATCH * HDIM + 255) / 256), dim3(256), 0, stream>>>(
            hglob, out + (size_t)BATCH * SEQ * VOCAB, BATCH * HDIM);
    }

    softmax_kernel<<<dim3(BATCH * SEQ), dim3(256), 0, stream>>>(out);
}